// Round 20
// baseline (42.625 us; speedup 1.0000x reference)
//
#include <hip/hip_runtime.h>
#include <hip/hip_fp16.h>

#define EPSF 1e-8f

typedef _Float16 half8 __attribute__((ext_vector_type(8)));
typedef float f32x4 __attribute__((ext_vector_type(4)));

// B=16, L=4096, I=64, H=512, O=1.
// TRUNCATION: a_t = 1-sigmoid(sigmoid(.)) < 0.5 always -> influence halves per step.
// Output = h1[:,L-1,:] @ Wf. Layer-1 window = last 64 steps (err <= 0.5^64*0.77 ~ 4e-20).
// Layer-0 on last 128 steps (64 warm-up + 64 live). SINGLE fused kernel:
// 128 blocks run layer-0 (+W1 transpose, W0 in-LDS), device-scope atomic grid
// barrier (all 128 co-resident on 256 CUs), then blocks 0..31 run layer-1+GEMV.

__device__ __forceinline__ float fast_rcp(float x) {
    return __builtin_amdgcn_rcpf(x);
}
// transform pre-activations -> (a, b) of recurrence h = a*h + b (division-free)
__device__ __forceinline__ void gate_transform(float pz, float ph, float& a, float& b) {
    float ez = __expf(-pz);
    float k  = fast_rcp(1.0f + ez);          // sigmoid(pz)
    float ek = __expf(-k);
    float z  = fast_rcp(1.0f + ek);          // sigmoid(k)
    a = ek * z;                              // 1 - z exactly
    float es = __expf(-ph);
    float s  = fast_rcp(1.0f + es);          // sigmoid(ph)
    float e2 = __expf(-2.0f * s);
    float hw = (1.0f - e2) * fast_rcp(1.0f + e2) + EPSF;  // tanh(s)+eps
    b = z * hw;
}

// async global->LDS, 16B per lane
__device__ __forceinline__ void gload16(const void* g, void* l) {
    __builtin_amdgcn_global_load_lds(
        (const __attribute__((address_space(1))) unsigned int*)g,
        (__attribute__((address_space(3))) unsigned int*)l, 16, 0, 0);
}

// Ordered affine compose across the 4 q-subgroups of a 64-lane wave.
__device__ __forceinline__ void qscan(int q, float pA, float pB,
                                      float& fA, float& fB, float& prA, float& prB)
{
    float oA = __shfl_xor(pA, 16, 64), oB = __shfl_xor(pB, 16, 64);
    float eA = (q & 1) ? oA : pA, eB = (q & 1) ? oB : pB;
    float lA = (q & 1) ? pA : oA, lB = (q & 1) ? pB : oB;
    float p2A = eA * lA;
    float p2B = fmaf(lA, eB, lB);
    float o2A = __shfl_xor(p2A, 32, 64), o2B = __shfl_xor(p2B, 32, 64);
    float loA = (q & 2) ? o2A : p2A, loB = (q & 2) ? o2B : p2B;
    float hiA = (q & 2) ? p2A : o2A, hiB = (q & 2) ? p2B : o2B;
    fA = loA * hiA;
    fB = fmaf(hiA, loB, hiB);
    prA = (q & 2) ? o2A : 1.0f;
    prB = (q & 2) ? o2B : 0.0f;
    if (q & 1) { prB = fmaf(oA, prB, oB); prA *= oA; }
}

// ---------------- fused kernel: layer-0 (all 128 blocks) -> grid barrier ->
// ---------------- layer-1 + output GEMV (blocks 0..31) ---------------------------
__global__ __launch_bounds__(256) void kfused(
    const float* __restrict__ x,
    const float* __restrict__ Wz0, const float* __restrict__ Wh0,
    const float* __restrict__ Wz1, const float* __restrict__ Wh1,
    const float* __restrict__ bz0, const float* __restrict__ bh0,
    const float* __restrict__ bz1, const float* __restrict__ bh1,
    const float* __restrict__ Wf, const float* __restrict__ bf,
    __half* __restrict__ Wtz1, __half* __restrict__ Wth1,
    __half* __restrict__ h0red, unsigned int* __restrict__ cnt,
    float* __restrict__ out)
{
    __shared__ char smem[49408];
    const int tid = threadIdx.x;
    const int wave = tid >> 6, lane = tid & 63;
    const int q = lane >> 4, l16 = lane & 15;
    const int wm = wave >> 1, wn = wave & 1;
    const int Lb = blockIdx.x;                 // 0..127

    // ================= PHASE 1: layer-0 on 128-step window =======================
    {
        __half* As = (__half*)smem;            // [128 rows][64 k] swizzled (16 KB)
        __half* Bs = As + 128 * 64;            // [128 rows][64 k]: <64 z, >=64 h (16 KB)
        float (*t)[65] = (float(*)[65])(smem + 32768);   // 64x65 f32 staging
        float* carray = (float*)(smem + 16384);          // overlay on Bs (post-MFMA)
        __half* h0s = (__half*)smem;                     // overlay on As (post-MFMA)

        const int bx = Lb & 7, by = Lb >> 3;   // n-tile, batch
        const int n0 = bx * 64;
        const float* xsrc = x + (size_t)by * 262144 + 253952;   // (4096-128)*64

        if (Lb == 0 && tid < 16) out[tid] = bf[0];   // phase-2 atomics add on top

        {   // stage A: x tail f32 -> fp16 ds_write into swizzled As
            const int r8 = lane >> 3, ch = lane & 7;
#pragma unroll
            for (int i = 0; i < 4; ++i) {
                const int reg = wave * 4 + i;
                const int row = reg * 8 + r8;
                const int c0 = (ch ^ (row & 7)) * 8;
                float4 v0 = *(const float4*)(xsrc + row * 64 + c0);
                float4 v1 = *(const float4*)(xsrc + row * 64 + c0 + 4);
                __half2* dst = (__half2*)((char*)As + reg * 1024 + lane * 16);
                dst[0] = __floats2half2_rn(v0.x, v0.y);
                dst[1] = __floats2half2_rn(v0.z, v0.w);
                dst[2] = __floats2half2_rn(v1.x, v1.y);
                dst[3] = __floats2half2_rn(v1.z, v1.w);
            }
        }

        const int r = tid >> 4, c4 = (tid & 15) * 4;
        {   // W1 transpose: this block's tile (mat = Lb>>6, ti = Lb&63)
            const int mat = Lb >> 6, ti = Lb & 63;
            const int n0t = (ti & 7) * 64, k0t = (ti >> 3) * 64;
            const float* W = mat ? Wh1 : Wz1;
            __half* Wt = mat ? Wth1 : Wtz1;
#pragma unroll
            for (int rr = 0; rr < 64; rr += 16)
                *(float4*)&t[rr + r][c4] = *(const float4*)&W[(size_t)(k0t + rr + r) * 512 + n0t + c4];
            __syncthreads();
#pragma unroll
            for (int rr = 0; rr < 64; rr += 16) {
                const int row = rr + r;
                __half2 h01 = __floats2half2_rn(t[c4 + 0][row], t[c4 + 1][row]);
                __half2 h23 = __floats2half2_rn(t[c4 + 2][row], t[c4 + 3][row]);
                *(__half2*)&Wt[(size_t)(n0t + row) * 512 + k0t + c4] = h01;
                *(__half2*)&Wt[(size_t)(n0t + row) * 512 + k0t + c4 + 2] = h23;
            }
        }
        {   // W0 staging: f32 tile -> t, transpose-convert into swizzled Bs
            const int n = tid & 63, cw = (tid >> 6) * 2;
#pragma unroll
            for (int mat = 0; mat < 2; ++mat) {
                const float* W = mat ? Wh0 : Wz0;
                __syncthreads();               // prev t reads done
#pragma unroll
                for (int rr = 0; rr < 64; rr += 16)
                    *(float4*)&t[rr + r][c4] = *(const float4*)&W[(size_t)(rr + r) * 512 + n0 + c4];
                __syncthreads();               // t loaded
#pragma unroll
                for (int cc = 0; cc < 2; ++cc) {
                    const int chunk = cw + cc;
                    half8 hv;
#pragma unroll
                    for (int j = 0; j < 8; ++j) hv[j] = (_Float16)t[chunk * 8 + j][n];
                    *(half8*)&Bs[(mat * 64 + n) * 64 + ((chunk ^ (n & 7)) << 3)] = hv;
                }
            }
        }
        __syncthreads();   // As + Bs ready

        f32x4 accz[4][2], acch[4][2];
#pragma unroll
        for (int mi = 0; mi < 4; ++mi)
#pragma unroll
            for (int ni = 0; ni < 2; ++ni) {
                accz[mi][ni] = (f32x4){0.f, 0.f, 0.f, 0.f};
                acch[mi][ni] = (f32x4){0.f, 0.f, 0.f, 0.f};
            }

#pragma unroll
        for (int s = 0; s < 2; ++s) {
            half8 af[4];
#pragma unroll
            for (int mi = 0; mi < 4; ++mi) {
                const int row = wm * 64 + mi * 16 + l16;
                const int pc = (s * 4 + q) ^ (row & 7);
                af[mi] = *(const half8*)&As[row * 64 + pc * 8];
            }
#pragma unroll
            for (int ni = 0; ni < 2; ++ni) {
                const int rn = wn * 32 + ni * 16 + l16;
                const int pc = (s * 4 + q) ^ (rn & 7);
                half8 bzf = *(const half8*)&Bs[rn * 64 + pc * 8];
                half8 bhf = *(const half8*)&Bs[(64 + rn) * 64 + pc * 8];
#pragma unroll
                for (int mi = 0; mi < 4; ++mi) {
                    accz[mi][ni] = __builtin_amdgcn_mfma_f32_16x16x32_f16(af[mi], bzf, accz[mi][ni], 0, 0, 0);
                    acch[mi][ni] = __builtin_amdgcn_mfma_f32_16x16x32_f16(af[mi], bhf, acch[mi][ni], 0, 0, 0);
                }
            }
        }

        // warm-up composite (wm=0): per-column 64-step B with H=0
        float rB[2];
        if (wm == 0) {
#pragma unroll
            for (int ni = 0; ni < 2; ++ni) {
                const int col = n0 + wn * 32 + ni * 16 + l16;
                const float bzv = bz0[col], bhv = bh0[col];
                float runA = 1.f, runB = 0.f;
#pragma unroll
                for (int mi = 0; mi < 4; ++mi) {
                    float av[4], bv[4], pA = 1.f, pB = 0.f;
#pragma unroll
                    for (int j = 0; j < 4; ++j) {
                        gate_transform(accz[mi][ni][j] + bzv, acch[mi][ni][j] + bhv, av[j], bv[j]);
                        pB = fmaf(av[j], pB, bv[j]); pA *= av[j];
                    }
                    float fA, fB, prA, prB;
                    qscan(q, pA, pB, fA, fB, prA, prB);
                    runB = fmaf(fA, runB, fB); runA *= fA;
                }
                rB[ni] = runB;
            }
        }
        __syncthreads();               // all waves done reading As/Bs
        if (wm == 0 && q == 0) {
#pragma unroll
            for (int ni = 0; ni < 2; ++ni)
                carray[wn * 32 + ni * 16 + l16] = rB[ni];
        }
        __syncthreads();               // carry visible
        if (wm == 1) {                 // live window: scan with carry -> h0s
#pragma unroll
            for (int ni = 0; ni < 2; ++ni) {
                const int colloc = wn * 32 + ni * 16 + l16;
                const int col = n0 + colloc;
                const float bzv = bz0[col], bhv = bh0[col];
                float H = carray[colloc];
#pragma unroll
                for (int mi = 0; mi < 4; ++mi) {
                    float av[4], bv[4], pA = 1.f, pB = 0.f;
#pragma unroll
                    for (int j = 0; j < 4; ++j) {
                        gate_transform(accz[mi][ni][j] + bzv, acch[mi][ni][j] + bhv, av[j], bv[j]);
                        pB = fmaf(av[j], pB, bv[j]); pA *= av[j];
                    }
                    float fA, fB, prA, prB;
                    qscan(q, pA, pB, fA, fB, prA, prB);
                    float Hl = fmaf(prA, H, prB);
                    const int rloc = mi * 16 + q * 4;
#pragma unroll
                    for (int j = 0; j < 4; ++j) {
                        Hl = fmaf(av[j], Hl, bv[j]);
                        h0s[(rloc + j) * 68 + colloc] = (__half)Hl;
                    }
                    H = fmaf(fA, H, fB);
                }
            }
        }
        __syncthreads();
        {   // coalesced writeout: 64 rows x 64 cols fp16
            const int row = tid >> 2, cpart = tid & 3;
            const __half* srcp = h0s + row * 68 + cpart * 16;
            __half* dstp = h0red + (size_t)(by * 64 + row) * 512 + n0 + cpart * 16;
            *(uint4*)dstp = *(const uint4*)srcp;
            *(uint4*)(dstp + 8) = *(const uint4*)(srcp + 8);
        }
    }

    // ================= GRID BARRIER (device-scope) ===============================
    __syncthreads();                   // all block stores drained (vmcnt before barrier)
    if (tid == 0) {
        __threadfence();               // L2 writeback, device scope (release)
        atomicAdd(cnt, 1u);
    }
    if (Lb >= 32) return;
    if (tid == 0) {
        while (__hip_atomic_load(cnt, __ATOMIC_RELAXED, __HIP_MEMORY_SCOPE_AGENT) < 128u)
            __builtin_amdgcn_s_sleep(2);
    }
    __syncthreads();
    __threadfence();                   // acquire: invalidate so cross-XCD writes visible

    // ================= PHASE 2: layer-1 + fused GEMV (blocks 0..31) ==============
    {
        char* smem4 = smem;            // [2][24576]: per buf A 8KB + B 16KB
        const int bx = Lb & 3, by = Lb >> 2;
        const int m0 = by * 128, n0 = bx * 128;
        const int r4 = lane >> 2, ch = lane & 3;

        const __half* aSrc[2]; int aDst[2];
#pragma unroll
        for (int i = 0; i < 2; ++i) {
            const int reg = wave * 2 + i;
            const int row = reg * 16 + r4;
            const int pc = ch ^ ((row >> 1) & 3);
            aSrc[i] = h0red + (size_t)(m0 + row) * 512 + pc * 8;
            aDst[i] = reg * 1024;
        }
        const __half* bSrc[4]; int bDst[4];
#pragma unroll
        for (int i = 0; i < 4; ++i) {
            const int reg = wave * 4 + i;
            const int row = reg * 16 + r4;
            const int pc = ch ^ ((row >> 1) & 3);
            bSrc[i] = ((row < 128) ? (Wtz1 + (size_t)(n0 + row) * 512)
                                   : (Wth1 + (size_t)(n0 + row - 128) * 512)) + pc * 8;
            bDst[i] = 8192 + reg * 1024;
        }
        int aOff[4], bOff[4];
#pragma unroll
        for (int mi = 0; mi < 4; ++mi) {
            const int row = wm * 64 + mi * 16 + l16;
            aOff[mi] = row * 64 + ((q ^ ((row >> 1) & 3)) << 4);
        }
#pragma unroll
        for (int ni = 0; ni < 4; ++ni) {
            const int rn = wn * 64 + ni * 16 + l16;
            bOff[ni] = 8192 + rn * 64 + ((q ^ ((rn >> 1) & 3)) << 4);
        }

        f32x4 accz[4][4], acch[4][4];
#pragma unroll
        for (int mi = 0; mi < 4; ++mi)
#pragma unroll
            for (int ni = 0; ni < 4; ++ni) {
                accz[mi][ni] = (f32x4){0.f, 0.f, 0.f, 0.f};
                acch[mi][ni] = (f32x4){0.f, 0.f, 0.f, 0.f};
            }

        auto stage = [&](int c, int t) {
#pragma unroll
            for (int i = 0; i < 2; ++i)
                gload16(aSrc[i] + t * 32, smem4 + c * 24576 + aDst[i]);
#pragma unroll
            for (int i = 0; i < 4; ++i)
                gload16(bSrc[i] + t * 32, smem4 + c * 24576 + bDst[i]);
        };
        auto compute = [&](int c) {
            half8 af[4];
#pragma unroll
            for (int mi = 0; mi < 4; ++mi)
                af[mi] = *(const half8*)(smem4 + c * 24576 + aOff[mi]);
            __builtin_amdgcn_s_setprio(1);
#pragma unroll
            for (int ni = 0; ni < 4; ++ni) {
                half8 bzf = *(const half8*)(smem4 + c * 24576 + bOff[ni]);
                half8 bhf = *(const half8*)(smem4 + c * 24576 + 8192 + bOff[ni]);
#pragma unroll
                for (int mi = 0; mi < 4; ++mi) {
                    accz[mi][ni] = __builtin_amdgcn_mfma_f32_16x16x32_f16(af[mi], bzf, accz[mi][ni], 0, 0, 0);
                    acch[mi][ni] = __builtin_amdgcn_mfma_f32_16x16x32_f16(af[mi], bhf, acch[mi][ni], 0, 0, 0);
                }
            }
            __builtin_amdgcn_s_setprio(0);
        };

        stage(0, 0);
#pragma unroll
        for (int t = 0; t < 15; ++t) {
            const int c = t & 1;
            stage(c ^ 1, t + 1);
            asm volatile("s_waitcnt vmcnt(6)" ::: "memory");
            __builtin_amdgcn_s_barrier();
            compute(c);
            __builtin_amdgcn_s_barrier();
        }
        asm volatile("s_waitcnt vmcnt(0)" ::: "memory");
        __builtin_amdgcn_s_barrier();
        compute(1);

        // epilogue: 64-step composite per batch (wm) -> h1[L-1]; fused GEMV with Wf
        const int batch = by * 2 + wm;
        float part = 0.f;
#pragma unroll
        for (int ni = 0; ni < 4; ++ni) {
            const int col = n0 + wn * 64 + ni * 16 + l16;
            const float bzv = bz1[col], bhv = bh1[col];
            float fullA = 1.f, fullB = 0.f;
#pragma unroll
            for (int mi = 0; mi < 4; ++mi) {
                float pA = 1.f, pB = 0.f;
#pragma unroll
                for (int j = 0; j < 4; ++j) {
                    float a, b;
                    gate_transform(accz[mi][ni][j] + bzv, acch[mi][ni][j] + bhv, a, b);
                    pB = fmaf(a, pB, b); pA *= a;
                }
                float fA, fB, prA, prB;
                qscan(q, pA, pB, fA, fB, prA, prB);
                fullB = fmaf(fA, fullB, fB); fullA *= fA;
            }
            if (q == 0) part = fmaf(fullB, Wf[col], part);
        }
#pragma unroll
        for (int off = 32; off; off >>= 1) part += __shfl_down(part, off, 64);
        if (lane == 0) atomicAdd(&out[batch], part);
    }
}

extern "C" void kernel_launch(void* const* d_in, const int* in_sizes, int n_in,
                              void* d_out, int out_size, void* d_ws, size_t ws_size,
                              hipStream_t stream)
{
    const float* x   = (const float*)d_in[0];
    const float* Wz0 = (const float*)d_in[1];
    const float* bz0 = (const float*)d_in[2];
    const float* Wh0 = (const float*)d_in[3];
    const float* bh0 = (const float*)d_in[4];
    const float* Wz1 = (const float*)d_in[5];
    const float* bz1 = (const float*)d_in[6];
    const float* Wh1 = (const float*)d_in[7];
    const float* bh1 = (const float*)d_in[8];
    const float* Wf  = (const float*)d_in[9];
    const float* bf  = (const float*)d_in[10];
    float* out = (float*)d_out;

    // workspace (~2 MiB + counter)
    char* ws = (char*)d_ws;
    __half* h0red = (__half*)ws;                           // 1 MiB: [1024][512]
    __half* Wtz1  = (__half*)(ws + (1024 << 10));          // 512 KiB
    __half* Wth1  = Wtz1 + 262144;                         // 512 KiB
    unsigned int* cnt = (unsigned int*)(ws + (2048 << 10));

    hipMemsetAsync(cnt, 0, sizeof(unsigned int), stream);
    kfused<<<128, 256, 0, stream>>>(x, Wz0, Wh0, Wz1, Wh1, bz0, bh0, bz1, bh1,
                                    Wf, bf, Wtz1, Wth1, h0red, cnt, out);
}

// Round 21
// 32.931 us; speedup vs baseline: 1.2944x; 1.2944x over previous
//
#include <hip/hip_runtime.h>
#include <hip/hip_fp16.h>

#define EPSF 1e-8f

typedef _Float16 half8 __attribute__((ext_vector_type(8)));
typedef float f32x4 __attribute__((ext_vector_type(4)));

// B=16, L=4096, I=64, H=512, O=1.
// TRUNCATION: a_t = 1-sigmoid(sigmoid(.)) < 0.5 always -> influence halves per step.
// Output = h1[:,L-1,:] @ Wf. Layer-1 window = last 64 steps (err <= 0.5^64*0.77 ~ 4e-20).
// Layer-0 computed on last 128 steps; first 64 = warm-up. TWO kernels total:
// k1s also transposes W1 (1:1 block<->tile) and stages W0 in-LDS (no kprep).

__device__ __forceinline__ float fast_rcp(float x) {
    return __builtin_amdgcn_rcpf(x);
}
// transform pre-activations -> (a, b) of recurrence h = a*h + b (division-free)
__device__ __forceinline__ void gate_transform(float pz, float ph, float& a, float& b) {
    float ez = __expf(-pz);
    float k  = fast_rcp(1.0f + ez);          // sigmoid(pz)
    float ek = __expf(-k);
    float z  = fast_rcp(1.0f + ek);          // sigmoid(k)
    a = ek * z;                              // 1 - z exactly
    float es = __expf(-ph);
    float s  = fast_rcp(1.0f + es);          // sigmoid(ph)
    float e2 = __expf(-2.0f * s);
    float hw = (1.0f - e2) * fast_rcp(1.0f + e2) + EPSF;  // tanh(s)+eps
    b = z * hw;
}

// async global->LDS, 16B per lane
__device__ __forceinline__ void gload16(const void* g, void* l) {
    __builtin_amdgcn_global_load_lds(
        (const __attribute__((address_space(1))) unsigned int*)g,
        (__attribute__((address_space(3))) unsigned int*)l, 16, 0, 0);
}

// Ordered affine compose across the 4 q-subgroups of a 64-lane wave.
__device__ __forceinline__ void qscan(int q, float pA, float pB,
                                      float& fA, float& fB, float& prA, float& prB)
{
    float oA = __shfl_xor(pA, 16, 64), oB = __shfl_xor(pB, 16, 64);
    float eA = (q & 1) ? oA : pA, eB = (q & 1) ? oB : pB;
    float lA = (q & 1) ? pA : oA, lB = (q & 1) ? pB : oB;
    float p2A = eA * lA;
    float p2B = fmaf(lA, eB, lB);
    float o2A = __shfl_xor(p2A, 32, 64), o2B = __shfl_xor(p2B, 32, 64);
    float loA = (q & 2) ? o2A : p2A, loB = (q & 2) ? o2B : p2B;
    float hiA = (q & 2) ? p2A : o2A, hiB = (q & 2) ? p2B : o2B;
    fA = loA * hiA;
    fB = fmaf(hiA, loB, hiB);
    prA = (q & 2) ? o2A : 1.0f;
    prB = (q & 2) ? o2B : 0.0f;
    if (q & 1) { prB = fmaf(oA, prB, oB); prA *= oA; }
}

// ---------------- k1s: layer-0 + W1 transpose + W0 in-LDS staging ----------------
// Grid (8,16) = 128 blocks. Block (bx,by): batch by, cols n0=bx*64, rows = last 128
// steps (wm=0 warm-up -> LDS carry, wm=1 live -> h0red). Additionally each block
// transposes ONE 64x64 tile of W1 (Lb = bx+8*by -> mat/tile) for k4.
__global__ __launch_bounds__(256) void k1s(
    const float* __restrict__ x,
    const float* __restrict__ Wz0, const float* __restrict__ Wh0,
    const float* __restrict__ Wz1, const float* __restrict__ Wh1,
    const float* __restrict__ bz, const float* __restrict__ bh,
    const float* __restrict__ bf,
    __half* __restrict__ Wtz1, __half* __restrict__ Wth1,
    __half* __restrict__ h0red, float* __restrict__ out)
{
    __shared__ char smem1[49408];
    __half* As = (__half*)smem1;               // [128 rows][64 k] swizzled (16 KB)
    __half* Bs = As + 128 * 64;                // [128 rows][64 k]: <64 z, >=64 h (16 KB)
    float (*t)[65] = (float(*)[65])(smem1 + 32768);   // 64x65 f32 staging (16.6 KB)
    float* carray = (float*)(smem1 + 16384);   // overlay on Bs; written post-MFMA
    __half* h0s = (__half*)smem1;              // overlay on As; written post-MFMA
    const int tid = threadIdx.x;
    const int wave = tid >> 6, lane = tid & 63;
    const int q = lane >> 4, l16 = lane & 15;
    const int wm = wave >> 1, wn = wave & 1;

    const int bx = blockIdx.x, by = blockIdx.y;
    const int Lb = bx + 8 * by;                // 0..127
    const int n0 = bx * 64;
    const float* xsrc = x + (size_t)by * 262144 + 253952;   // (4096-128)*64

    if (Lb == 0 && tid < 16) out[tid] = bf[0];  // k4 atomics accumulate on top

    {   // stage A: x tail f32 -> fp16 ds_write into swizzled As
        const int r8 = lane >> 3, ch = lane & 7;
#pragma unroll
        for (int i = 0; i < 4; ++i) {
            const int reg = wave * 4 + i;
            const int row = reg * 8 + r8;
            const int c0 = (ch ^ (row & 7)) * 8;
            float4 v0 = *(const float4*)(xsrc + row * 64 + c0);
            float4 v1 = *(const float4*)(xsrc + row * 64 + c0 + 4);
            __half2* dst = (__half2*)((char*)As + reg * 1024 + lane * 16);
            dst[0] = __floats2half2_rn(v0.x, v0.y);
            dst[1] = __floats2half2_rn(v0.z, v0.w);
            dst[2] = __floats2half2_rn(v1.x, v1.y);
            dst[3] = __floats2half2_rn(v1.z, v1.w);
        }
    }

    const int r = tid >> 4, c4 = (tid & 15) * 4;
    {   // W1 transpose: this block's tile (mat = Lb>>6, ti = Lb&63)
        const int mat = Lb >> 6, ti = Lb & 63;
        const int n0t = (ti & 7) * 64, k0t = (ti >> 3) * 64;
        const float* W = mat ? Wh1 : Wz1;
        __half* Wt = mat ? Wth1 : Wtz1;
#pragma unroll
        for (int rr = 0; rr < 64; rr += 16)
            *(float4*)&t[rr + r][c4] = *(const float4*)&W[(size_t)(k0t + rr + r) * 512 + n0t + c4];
        __syncthreads();
#pragma unroll
        for (int rr = 0; rr < 64; rr += 16) {
            const int row = rr + r;
            __half2 h01 = __floats2half2_rn(t[c4 + 0][row], t[c4 + 1][row]);
            __half2 h23 = __floats2half2_rn(t[c4 + 2][row], t[c4 + 3][row]);
            *(__half2*)&Wt[(size_t)(n0t + row) * 512 + k0t + c4] = h01;
            *(__half2*)&Wt[(size_t)(n0t + row) * 512 + k0t + c4 + 2] = h23;
        }
    }
    {   // W0 staging: load f32 tile -> t, transpose-convert into swizzled Bs
        const int n = tid & 63, cw = (tid >> 6) * 2;
#pragma unroll
        for (int mat = 0; mat < 2; ++mat) {
            const float* W = mat ? Wh0 : Wz0;
            __syncthreads();                   // prev t reads done
#pragma unroll
            for (int rr = 0; rr < 64; rr += 16)
                *(float4*)&t[rr + r][c4] = *(const float4*)&W[(size_t)(rr + r) * 512 + n0 + c4];
            __syncthreads();                   // t loaded
#pragma unroll
            for (int cc = 0; cc < 2; ++cc) {
                const int chunk = cw + cc;     // logical k-chunk 0..7
                half8 hv;
#pragma unroll
                for (int j = 0; j < 8; ++j) hv[j] = (_Float16)t[chunk * 8 + j][n];
                *(half8*)&Bs[(mat * 64 + n) * 64 + ((chunk ^ (n & 7)) << 3)] = hv;
            }
        }
    }
    __syncthreads();   // As + Bs ready

    f32x4 accz[4][2], acch[4][2];
#pragma unroll
    for (int mi = 0; mi < 4; ++mi)
#pragma unroll
        for (int ni = 0; ni < 2; ++ni) {
            accz[mi][ni] = (f32x4){0.f, 0.f, 0.f, 0.f};
            acch[mi][ni] = (f32x4){0.f, 0.f, 0.f, 0.f};
        }

#pragma unroll
    for (int s = 0; s < 2; ++s) {
        half8 af[4];
#pragma unroll
        for (int mi = 0; mi < 4; ++mi) {
            const int row = wm * 64 + mi * 16 + l16;
            const int pc = (s * 4 + q) ^ (row & 7);
            af[mi] = *(const half8*)&As[row * 64 + pc * 8];
        }
#pragma unroll
        for (int ni = 0; ni < 2; ++ni) {
            const int rn = wn * 32 + ni * 16 + l16;
            const int pc = (s * 4 + q) ^ (rn & 7);
            half8 bzf = *(const half8*)&Bs[rn * 64 + pc * 8];
            half8 bhf = *(const half8*)&Bs[(64 + rn) * 64 + pc * 8];
#pragma unroll
            for (int mi = 0; mi < 4; ++mi) {
                accz[mi][ni] = __builtin_amdgcn_mfma_f32_16x16x32_f16(af[mi], bzf, accz[mi][ni], 0, 0, 0);
                acch[mi][ni] = __builtin_amdgcn_mfma_f32_16x16x32_f16(af[mi], bhf, acch[mi][ni], 0, 0, 0);
            }
        }
    }

    // ---- warm-up composite (wm=0): per-column 64-step B with H=0 ----
    float rB[2];
    if (wm == 0) {
#pragma unroll
        for (int ni = 0; ni < 2; ++ni) {
            const int col = n0 + wn * 32 + ni * 16 + l16;
            const float bzv = bz[col], bhv = bh[col];
            float runA = 1.f, runB = 0.f;
#pragma unroll
            for (int mi = 0; mi < 4; ++mi) {
                float av[4], bv[4], pA = 1.f, pB = 0.f;
#pragma unroll
                for (int j = 0; j < 4; ++j) {
                    gate_transform(accz[mi][ni][j] + bzv, acch[mi][ni][j] + bhv, av[j], bv[j]);
                    pB = fmaf(av[j], pB, bv[j]); pA *= av[j];
                }
                float fA, fB, prA, prB;
                qscan(q, pA, pB, fA, fB, prA, prB);
                runB = fmaf(fA, runB, fB); runA *= fA;
            }
            rB[ni] = runB;
        }
    }
    __syncthreads();                   // all waves done reading As/Bs
    if (wm == 0 && q == 0) {
#pragma unroll
        for (int ni = 0; ni < 2; ++ni)
            carray[wn * 32 + ni * 16 + l16] = rB[ni];
    }
    __syncthreads();                   // carry visible
    // ---- live window (wm=1): scan with carry, stage rows into h0s ----
    if (wm == 1) {
#pragma unroll
        for (int ni = 0; ni < 2; ++ni) {
            const int colloc = wn * 32 + ni * 16 + l16;
            const int col = n0 + colloc;
            const float bzv = bz[col], bhv = bh[col];
            float H = carray[colloc];
#pragma unroll
            for (int mi = 0; mi < 4; ++mi) {
                float av[4], bv[4], pA = 1.f, pB = 0.f;
#pragma unroll
                for (int j = 0; j < 4; ++j) {
                    gate_transform(accz[mi][ni][j] + bzv, acch[mi][ni][j] + bhv, av[j], bv[j]);
                    pB = fmaf(av[j], pB, bv[j]); pA *= av[j];
                }
                float fA, fB, prA, prB;
                qscan(q, pA, pB, fA, fB, prA, prB);
                float Hl = fmaf(prA, H, prB);
                const int rloc = mi * 16 + q * 4;      // 0..63
#pragma unroll
                for (int j = 0; j < 4; ++j) {
                    Hl = fmaf(av[j], Hl, bv[j]);
                    h0s[(rloc + j) * 68 + colloc] = (__half)Hl;
                }
                H = fmaf(fA, H, fB);
            }
        }
    }
    __syncthreads();
    {   // coalesced writeout: 64 rows x 64 cols fp16
        const int row = tid >> 2, cpart = tid & 3;
        const __half* srcp = h0s + row * 68 + cpart * 16;
        __half* dstp = h0red + (size_t)(by * 64 + row) * 512 + n0 + cpart * 16;
        *(uint4*)dstp = *(const uint4*)srcp;
        *(uint4*)(dstp + 8) = *(const uint4*)(srcp + 8);
    }
}

// ---------------- k4: layer-1 MFMA + fused output GEMV ----------------------------
// Grid (4, 8): m-tile 128 rows = 2 batches (wm = batch parity), n-tile 128 cols.
// r16 loop (counted vmcnt(6), raw barriers, (256,2) clamp, unrolled, hoisted).
// Epilogue: per-batch 64-step composite B == h1[L-1]; partial dot with Wf,
// wave-reduce, atomicAdd into out[batch] (init'd to bf by k1s).
__global__ __launch_bounds__(256, 2) void k4_l1(
    const __half* __restrict__ h0red,
    const __half* __restrict__ Wtz, const __half* __restrict__ Wth,  // [512][512] fp16
    const float* __restrict__ bz, const float* __restrict__ bh,
    const float* __restrict__ Wf, float* __restrict__ out)
{
    __shared__ char smem4[2][24576];     // per buf: A 8KB (128x32) + B 16KB (256x32)
    const int tid = threadIdx.x;
    const int wave = tid >> 6, lane = tid & 63;
    const int q = lane >> 4, l16 = lane & 15;
    const int wm = wave >> 1, wn = wave & 1;

    const int bx = blockIdx.x, by = blockIdx.y;
    const int m0 = by * 128, n0 = bx * 128;

    const int r4 = lane >> 2, ch = lane & 3;

    const __half* aSrc[2]; int aDst[2];
#pragma unroll
    for (int i = 0; i < 2; ++i) {
        const int reg = wave * 2 + i;
        const int row = reg * 16 + r4;
        const int pc = ch ^ ((row >> 1) & 3);
        aSrc[i] = h0red + (size_t)(m0 + row) * 512 + pc * 8;
        aDst[i] = reg * 1024;
    }
    const __half* bSrc[4]; int bDst[4];
#pragma unroll
    for (int i = 0; i < 4; ++i) {
        const int reg = wave * 4 + i;
        const int row = reg * 16 + r4;
        const int pc = ch ^ ((row >> 1) & 3);
        bSrc[i] = ((row < 128) ? (Wtz + (size_t)(n0 + row) * 512)
                               : (Wth + (size_t)(n0 + row - 128) * 512)) + pc * 8;
        bDst[i] = 8192 + reg * 1024;
    }
    int aOff[4], bOff[4];
#pragma unroll
    for (int mi = 0; mi < 4; ++mi) {
        const int row = wm * 64 + mi * 16 + l16;
        aOff[mi] = row * 64 + ((q ^ ((row >> 1) & 3)) << 4);
    }
#pragma unroll
    for (int ni = 0; ni < 4; ++ni) {
        const int rn = wn * 64 + ni * 16 + l16;
        bOff[ni] = 8192 + rn * 64 + ((q ^ ((rn >> 1) & 3)) << 4);
    }

    f32x4 accz[4][4], acch[4][4];
#pragma unroll
    for (int mi = 0; mi < 4; ++mi)
#pragma unroll
        for (int ni = 0; ni < 4; ++ni) {
            accz[mi][ni] = (f32x4){0.f, 0.f, 0.f, 0.f};
            acch[mi][ni] = (f32x4){0.f, 0.f, 0.f, 0.f};
        }

    auto stage = [&](int c, int t) {
#pragma unroll
        for (int i = 0; i < 2; ++i)
            gload16(aSrc[i] + t * 32, smem4[c] + aDst[i]);
#pragma unroll
        for (int i = 0; i < 4; ++i)
            gload16(bSrc[i] + t * 32, smem4[c] + bDst[i]);
    };
    auto compute = [&](int c) {
        half8 af[4];
#pragma unroll
        for (int mi = 0; mi < 4; ++mi)
            af[mi] = *(const half8*)(smem4[c] + aOff[mi]);
        __builtin_amdgcn_s_setprio(1);
#pragma unroll
        for (int ni = 0; ni < 4; ++ni) {
            half8 bzf = *(const half8*)(smem4[c] + bOff[ni]);
            half8 bhf = *(const half8*)(smem4[c] + 8192 + bOff[ni]);
#pragma unroll
            for (int mi = 0; mi < 4; ++mi) {
                accz[mi][ni] = __builtin_amdgcn_mfma_f32_16x16x32_f16(af[mi], bzf, accz[mi][ni], 0, 0, 0);
                acch[mi][ni] = __builtin_amdgcn_mfma_f32_16x16x32_f16(af[mi], bhf, acch[mi][ni], 0, 0, 0);
            }
        }
        __builtin_amdgcn_s_setprio(0);
    };

    stage(0, 0);
#pragma unroll
    for (int t = 0; t < 15; ++t) {
        const int c = t & 1;
        stage(c ^ 1, t + 1);
        asm volatile("s_waitcnt vmcnt(6)" ::: "memory");
        __builtin_amdgcn_s_barrier();
        compute(c);
        __builtin_amdgcn_s_barrier();
    }
    asm volatile("s_waitcnt vmcnt(0)" ::: "memory");
    __builtin_amdgcn_s_barrier();
    compute(1);

    // epilogue: 64-step composite per batch (wm) -> h1[L-1]; fused GEMV with Wf
    const int batch = by * 2 + wm;
    float part = 0.f;
#pragma unroll
    for (int ni = 0; ni < 4; ++ni) {
        const int col = n0 + wn * 64 + ni * 16 + l16;
        const float bzv = bz[col], bhv = bh[col];
        float fullA = 1.f, fullB = 0.f;
#pragma unroll
        for (int mi = 0; mi < 4; ++mi) {
            float pA = 1.f, pB = 0.f;
#pragma unroll
            for (int j = 0; j < 4; ++j) {
                float a, b;
                gate_transform(accz[mi][ni][j] + bzv, acch[mi][ni][j] + bhv, a, b);
                pB = fmaf(a, pB, b); pA *= a;
            }
            float fA, fB, prA, prB;
            qscan(q, pA, pB, fA, fB, prA, prB);
            fullB = fmaf(fA, fullB, fB); fullA *= fA;
        }
        if (q == 0) part = fmaf(fullB, Wf[col], part);
    }
#pragma unroll
    for (int off = 32; off; off >>= 1) part += __shfl_down(part, off, 64);
    if (lane == 0) atomicAdd(&out[batch], part);
}

extern "C" void kernel_launch(void* const* d_in, const int* in_sizes, int n_in,
                              void* d_out, int out_size, void* d_ws, size_t ws_size,
                              hipStream_t stream)
{
    const float* x   = (const float*)d_in[0];
    const float* Wz0 = (const float*)d_in[1];
    const float* bz0 = (const float*)d_in[2];
    const float* Wh0 = (const float*)d_in[3];
    const float* bh0 = (const float*)d_in[4];
    const float* Wz1 = (const float*)d_in[5];
    const float* bz1 = (const float*)d_in[6];
    const float* Wh1 = (const float*)d_in[7];
    const float* bh1 = (const float*)d_in[8];
    const float* Wf  = (const float*)d_in[9];
    const float* bf  = (const float*)d_in[10];
    float* out = (float*)d_out;

    // workspace (~2 MiB)
    char* ws = (char*)d_ws;
    __half* h0red = (__half*)ws;                           // 1 MiB: [1024][512]
    __half* Wtz1  = (__half*)(ws + (1024 << 10));          // 512 KiB
    __half* Wth1  = Wtz1 + 262144;                         // 512 KiB

    k1s<<<dim3(8, 16), 256, 0, stream>>>(x, Wz0, Wh0, Wz1, Wh1, bz0, bh0, bf,
                                         Wtz1, Wth1, h0red, out);
    k4_l1<<<dim3(4, 8), 256, 0, stream>>>(h0red, Wtz1, Wth1, bz1, bh1, Wf, out);
}